// Round 1
// baseline (581.872 us; speedup 1.0000x reference)
//
#include <hip/hip_runtime.h>

// CRF forward-score + gold-score, MI355X.
//
// Exp-domain formulation: E = exp(T) precomputed in VGPRs (lane i holds row i),
// beta_t[i] = exp(alpha_t[i] - alpha_t[0]) maintained in fp32 with per-step
// renormalization by the lane-0 component; L accumulates log(z_0) + u_0 so
// alpha_t[i] = log(beta_t[i]) + L_t. The -10000 sentinels underflow to exact
// zeros in E, matching the fp32 reference's own underflow (no max-shift needed).
//
// One wave per batch element (lane = tag index), 64-thread blocks, 1024 blocks
// -> 1 wave per SIMD machine-wide. Feat loads coalesced + depth-8 prefetch.

#define BB 1024
#define TT 512
#define KK 64
#define START_TAG 62

__global__ __launch_bounds__(64) void crf_forward_kernel(
    const float* __restrict__ feats,   // [B, T, K]
    const int*   __restrict__ tags,    // [B, T]
    const float* __restrict__ trans,   // [K, K]  trans[i*K+j] = score j -> i
    float*       __restrict__ diff)    // [B]  forward - gold
{
  __shared__ float sbeta[KK];
  const int lane = threadIdx.x;        // 0..63 == tag index
  const int b    = blockIdx.x;         // batch element

  // ---- precompute E row: e4[jc] = exp(trans[lane][4jc .. 4jc+3]) ----
  float4 e4[16];
  const float4* trow = (const float4*)(trans + lane * KK);
  #pragma unroll
  for (int jc = 0; jc < 16; ++jc) {
    float4 tv = trow[jc];
    e4[jc].x = __expf(tv.x);
    e4[jc].y = __expf(tv.y);
    e4[jc].z = __expf(tv.z);
    e4[jc].w = __expf(tv.w);
  }

  const float* fb = feats + (size_t)b * TT * KK + lane;

  // ---- depth-8 feat prefetch ring (slots static under unroll-8) ----
  float upf[8];
  #pragma unroll
  for (int d = 0; d < 8; ++d) upf[d] = fb[(size_t)(1 + d) * KK];

  // beta_0 = exp(alpha_0): 1 at START, exp(-10000)=0 elsewhere. L_0 = 0.
  float beta = (lane == START_TAG) ? 1.0f : 0.0f;
  float L = 0.0f;

  const float4* sb4 = (const float4*)sbeta;

  #pragma unroll 8
  for (int t = 1; t < TT; ++t) {
    sbeta[lane] = beta;
    __syncthreads();

    float u = upf[(t - 1) & 7];                    // feat_t[lane]
    int tn = t + 8; if (tn > TT - 1) tn = TT - 1;  // refill slot for t+8
    upf[(t - 1) & 7] = fb[(size_t)tn * KK];

    // z_i = sum_j E[i][j] * beta[j] — 8 independent FMA chains
    float4 a0 = {0.f, 0.f, 0.f, 0.f};
    float4 a1 = {0.f, 0.f, 0.f, 0.f};
    #pragma unroll
    for (int jc = 0; jc < 16; jc += 2) {
      float4 bv0 = sb4[jc];
      float4 bv1 = sb4[jc + 1];
      a0.x = fmaf(e4[jc].x,     bv0.x, a0.x);
      a0.y = fmaf(e4[jc].y,     bv0.y, a0.y);
      a0.z = fmaf(e4[jc].z,     bv0.z, a0.z);
      a0.w = fmaf(e4[jc].w,     bv0.w, a0.w);
      a1.x = fmaf(e4[jc + 1].x, bv1.x, a1.x);
      a1.y = fmaf(e4[jc + 1].y, bv1.y, a1.y);
      a1.z = fmaf(e4[jc + 1].z, bv1.z, a1.z);
      a1.w = fmaf(e4[jc + 1].w, bv1.w, a1.w);
    }
    float z = ((a0.x + a1.x) + (a0.y + a1.y)) + ((a0.z + a1.z) + (a0.w + a1.w));

    // renormalize by lane-0 component; accumulate log-partition along row 0
    float z0 = __shfl(z, 0);
    float u0 = __shfl(u, 0);
    float f  = __expf(u - u0);
    beta = z * __builtin_amdgcn_rcpf(z0) * f;
    L   += __logf(z0) + u0;
    __syncthreads();   // protect sbeta before next iteration's write
  }

  // forward score = log(sum_j beta) + L   (beta[0] == 1 so sum >= 1)
  float bs = beta;
  #pragma unroll
  for (int off = 32; off; off >>= 1) bs += __shfl_xor(bs, off);
  float fwd = __logf(bs) + L;

  // ---- gold path score ----
  const int* tg = tags + b * TT;
  float gs = 0.0f;
  for (int tt = 1 + lane; tt < TT; tt += 64) {
    int tc = tg[tt];
    int tp = tg[tt - 1];
    gs += trans[tc * KK + tp]
        + feats[(size_t)b * TT * KK + (size_t)tt * KK + tc];
  }
  #pragma unroll
  for (int off = 32; off; off >>= 1) gs += __shfl_xor(gs, off);

  if (lane == 0) diff[b] = fwd - gs;
}

__global__ __launch_bounds__(1024) void reduce_mean_kernel(
    const float* __restrict__ diff, float* __restrict__ out)
{
  __shared__ float part[16];
  const int tid = threadIdx.x;
  float v = diff[tid];
  #pragma unroll
  for (int off = 32; off; off >>= 1) v += __shfl_xor(v, off);
  if ((tid & 63) == 0) part[tid >> 6] = v;
  __syncthreads();
  if (tid < 16) {
    float s = part[tid];
    #pragma unroll
    for (int off = 8; off; off >>= 1) s += __shfl_xor(s, off);
    if (tid == 0) out[0] = s * (1.0f / 1024.0f);
  }
}

extern "C" void kernel_launch(void* const* d_in, const int* in_sizes, int n_in,
                              void* d_out, int out_size, void* d_ws, size_t ws_size,
                              hipStream_t stream) {
  const float* feats = (const float*)d_in[0];
  const int*   tags  = (const int*)d_in[1];
  const float* trans = (const float*)d_in[2];
  float* out  = (float*)d_out;
  float* diff = (float*)d_ws;   // 1024 floats of scratch

  crf_forward_kernel<<<dim3(BB), dim3(64), 0, stream>>>(feats, tags, trans, diff);
  reduce_mean_kernel<<<dim3(1), dim3(1024), 0, stream>>>(diff, out);
}

// Round 3
// 314.152 us; speedup vs baseline: 1.8522x; 1.8522x over previous
//
#include <hip/hip_runtime.h>

// CRF forward-score + gold-score, MI355X (gfx950).
//
// Exp-domain: E = exp(T) lives in 64 VGPRs per lane (lane i = row i).
// beta_t[i] = exp(alpha_t[i] - C_t) maintained in fp32.
//
// Normalization: FRESH power-of-two scale. After z = E.beta is computed,
//   e_t  = exponent field of z0 (= readfirstlane(z))
//   s_t  = 2^{-(e_t-127)}  (bits: 0x7F000000 - (zbits & 0x7F800000))
//   beta = z * exp(u_t - u_t[0]) * s_t ,  C_t = C_{t-1} + u_t[0] + e'_t*ln2
// Fresh => memoryless => stable (R2's STALE 1/z0_{t-1} normalizer is a
// marginally-stable oscillator b_t = b_{t-1} - b_{t-2} + noise, |roots|=1,
// random-walks to overflow -> NaN). Power-of-two => mul exact, no log/rcp
// on the critical path at all. beta[0] in [1,2); spread <= e^21; z <= ~1e13
// -- all comfortably fp32. Sentinels (-10000) underflow to exact 0 in E,
// matching the fp32 reference's own underflow.
//
// Stale FEAT precompute is kept (fs = exp(u_{t+1}-u_{t+1}[0]) computed one
// step early): feats don't depend on the recursion, so no stability issue.
//
// One wave per batch: 1024 blocks x 64 threads -> 1 wave/SIMD machine-wide.
// __launch_bounds__(64, 1) REQUIRED: without ",1" the compiler caps at 64
// VGPRs and spills E to scratch (R1: 450 us, VGPR_Count=64).
// No __syncthreads: block == 1 wave; same-wave LDS ops execute in order;
// sbeta double-buffered so next-step write can't race current-step reads.
// Feat prefetch ring depth 7, outer 73 x inner unroll 7 (511 = 7*73) so
// ring indices constant-fold (no scratch).

#define BB 1024
#define TT 512
#define KK 64
#define START_TAG 62

__global__ __launch_bounds__(64, 1) void crf_forward_kernel(
    const float* __restrict__ feats,   // [B, T, K]
    const int*   __restrict__ tags,    // [B, T]
    const float* __restrict__ trans,   // [K, K]  trans[i*K+j] = score j -> i
    float*       __restrict__ diff)    // [B]  forward - gold
{
  __shared__ float sbeta[2][KK];
  const int lane = threadIdx.x;        // 0..63 == tag index
  const int b    = blockIdx.x;

  // ---- E row in registers: e4[jc] = exp(trans[lane][4jc..4jc+3]) ----
  float4 e4[16];
  {
    const float4* trow = (const float4*)(trans + lane * KK);
    #pragma unroll
    for (int jc = 0; jc < 16; ++jc) {
      float4 tv = trow[jc];
      e4[jc] = make_float4(__expf(tv.x), __expf(tv.y),
                           __expf(tv.z), __expf(tv.w));
    }
  }

  const float* fb = feats + (size_t)b * TT * KK + lane;

  // ---- prefetch ring: slot (t-1)%7 holds u_t ----
  float upf[7];
  #pragma unroll
  for (int d = 0; d < 7; ++d) upf[d] = fb[(size_t)(1 + d) * KK];

  float beta = (lane == START_TAG) ? 1.0f : 0.0f;
  float L = 0.0f;

  // f_cur for t=1: exp(u_1 - u_1[0])
  float u_1    = upf[0];
  float u0_cur = __uint_as_float(
      __builtin_amdgcn_readfirstlane(__float_as_uint(u_1)));
  float f_cur  = __expf(u_1 - u0_cur);

  sbeta[1][lane] = beta;   // first iter (t=1) reads buffer t&1 == 1

  const float LN2 = 0.6931471805599453f;

  for (int g = 0; g < 73; ++g) {
    #pragma unroll
    for (int d = 0; d < 7; ++d) {
      const int t = 1 + g * 7 + d;
      const float4* sb4 = (const float4*)sbeta[t & 1];

      // z_i = sum_j E[i][j] * beta[j] — 8 independent FMA chains,
      // LDS reads are same-address broadcasts (conflict-free).
      float4 a0 = {0.f, 0.f, 0.f, 0.f};
      float4 a1 = {0.f, 0.f, 0.f, 0.f};
      #pragma unroll
      for (int jc = 0; jc < 16; jc += 2) {
        float4 bv0 = sb4[jc];
        float4 bv1 = sb4[jc + 1];
        a0.x = fmaf(e4[jc].x,     bv0.x, a0.x);
        a0.y = fmaf(e4[jc].y,     bv0.y, a0.y);
        a0.z = fmaf(e4[jc].z,     bv0.z, a0.z);
        a0.w = fmaf(e4[jc].w,     bv0.w, a0.w);
        a1.x = fmaf(e4[jc + 1].x, bv1.x, a1.x);
        a1.y = fmaf(e4[jc + 1].y, bv1.y, a1.y);
        a1.z = fmaf(e4[jc + 1].z, bv1.z, a1.z);
        a1.w = fmaf(e4[jc + 1].w, bv1.w, a1.w);
      }
      float z = ((a0.x + a1.x) + (a0.y + a1.y)) +
                ((a0.z + a1.z) + (a0.w + a1.w));

      // refill slot d with u_{t+7}
      int tn = t + 7; if (tn > TT - 1) tn = TT - 1;
      upf[d] = fb[(size_t)tn * KK];

      // ---- fresh power-of-two normalization (critical-path tail) ----
      unsigned zb = __builtin_amdgcn_readfirstlane(__float_as_uint(z));
      float s = __uint_as_float(0x7F000000u - (zb & 0x7F800000u)); // 2^-(e-127)
      beta = (z * f_cur) * s;                 // z*f issues before s is ready
      sbeta[(t + 1) & 1][lane] = beta;

      // ---- off-chain: L accumulation + next step's feat factor ----
      int epow = (int)((zb >> 23) & 0xFFu) - 127;
      L += u0_cur + (float)epow * LN2;        // exact pow2 accounting
      float un = (d < 6) ? upf[d + 1] : upf[0];       // u_{t+1}
      float u0n = __uint_as_float(
          __builtin_amdgcn_readfirstlane(__float_as_uint(un)));
      f_cur = __expf(un - u0n);
      u0_cur = u0n;
    }
  }

  // forward score = log(sum_j beta) + L   (beta[0] in [1,2) => sum >= 1)
  float bs = beta;
  #pragma unroll
  for (int off = 32; off; off >>= 1) bs += __shfl_xor(bs, off);
  float fwd = __logf(bs) + L;

  // ---- gold path score ----
  const int* tg = tags + b * TT;
  float gs = 0.0f;
  for (int tt = 1 + lane; tt < TT; tt += 64) {
    int tc = tg[tt];
    int tp = tg[tt - 1];
    gs += trans[tc * KK + tp]
        + feats[(size_t)b * TT * KK + (size_t)tt * KK + tc];
  }
  #pragma unroll
  for (int off = 32; off; off >>= 1) gs += __shfl_xor(gs, off);

  if (lane == 0) diff[b] = fwd - gs;
}

__global__ __launch_bounds__(1024) void reduce_mean_kernel(
    const float* __restrict__ diff, float* __restrict__ out)
{
  __shared__ float part[16];
  const int tid = threadIdx.x;
  float v = diff[tid];
  #pragma unroll
  for (int off = 32; off; off >>= 1) v += __shfl_xor(v, off);
  if ((tid & 63) == 0) part[tid >> 6] = v;
  __syncthreads();
  if (tid < 16) {
    float s = part[tid];
    #pragma unroll
    for (int off = 8; off; off >>= 1) s += __shfl_xor(s, off);
    if (tid == 0) out[0] = s * (1.0f / 1024.0f);
  }
}

extern "C" void kernel_launch(void* const* d_in, const int* in_sizes, int n_in,
                              void* d_out, int out_size, void* d_ws, size_t ws_size,
                              hipStream_t stream) {
  const float* feats = (const float*)d_in[0];
  const int*   tags  = (const int*)d_in[1];
  const float* trans = (const float*)d_in[2];
  float* out  = (float*)d_out;
  float* diff = (float*)d_ws;   // 1024 floats of scratch

  crf_forward_kernel<<<dim3(BB), dim3(64), 0, stream>>>(feats, tags, trans, diff);
  reduce_mean_kernel<<<dim3(1), dim3(1024), 0, stream>>>(diff, out);
}

// Round 4
// 283.570 us; speedup vs baseline: 2.0520x; 1.1078x over previous
//
#include <hip/hip_runtime.h>

// CRF forward-score + gold-score, MI355X (gfx950).
//
// R4: LDS fully removed from the recurrence. R3 was bottlenecked by the
// per-CU LDS pipe: 4 waves/CU x 16 ds_read_b128/step x ~12cyc = ~770
// cyc/step (observed 869), VALUBusy only 45%. The beta all-gather is now
// done with v_readlane -> SGPR, and each SGPR feeds v_fmac_f32 directly
// (1 scalar operand per VALU instr is legal). Per step: 64 readlane +
// 64 fmac + ~10 misc VALU on a PRIVATE SIMD (1 wave/SIMD machine-wide).
//
// Exp-domain recurrence with fresh power-of-two normalization:
//   beta_t = exp(alpha_t - C_t),  C_t = C_{t-1} + e_t*ln2
//   z_t[i] = sum_j E[i][j] * beta_{t-1}[j]     (E = exp(T), in 64 VGPRs)
//   e_t    = exponent(z_t[0])                  (readlane 0, SALU extract)
//   beta_t = z_t * exp(u_t) * 2^{-e_t}
// Fresh normalizer => memoryless => stable (the R2 stale-normalizer NaN
// was a |root|=1 oscillator). No u0 subtraction needed: exp(u) in e^±5,
// and the pow2 scale absorbs growth; beta <= ~7e6, z <= ~6e10 (fp32-safe).
// e_t accumulates in an INT (exact); L = esum*ln2 applied once at the end.
// Sentinels (-10000) underflow to exact 0 in E, matching the fp32
// reference's own underflow (row START all-zero => beta[START]=0 forever,
// col STOP never read into z — consistent with reference).
//
// One wave per batch: 1024 blocks x 64 threads -> 1 wave/SIMD.
// __launch_bounds__(64,1) REQUIRED: without ",1" the compiler caps at 64
// VGPRs and spills E to scratch (R1: 450 us).
// Feat prefetch ring depth 7, outer 73 x inner unroll 7 (511 = 7*73) so
// ring indices constant-fold. exp(u_{t+1}) precomputed one step early
// (feats don't feed back -> no stability issue).

#define BB 1024
#define TT 512
#define KK 64
#define START_TAG 62

// broadcast lane l's float to all lanes via SGPR (l must be a literal 0..63)
#define RLF(v, l) __uint_as_float((unsigned)__builtin_amdgcn_readlane((int)__float_as_uint(v), (l)))

__global__ __launch_bounds__(64, 1) void crf_forward_kernel(
    const float* __restrict__ feats,   // [B, T, K]
    const int*   __restrict__ tags,    // [B, T]
    const float* __restrict__ trans,   // [K, K]  trans[i*K+j] = score j -> i
    float*       __restrict__ diff)    // [B]  forward - gold
{
  const int lane = threadIdx.x;        // 0..63 == tag index
  const int b    = blockIdx.x;

  // ---- E row in registers: e4[jc] = exp(trans[lane][4jc..4jc+3]) ----
  float4 e4[16];
  {
    const float4* trow = (const float4*)(trans + lane * KK);
    #pragma unroll
    for (int jc = 0; jc < 16; ++jc) {
      float4 tv = trow[jc];
      e4[jc] = make_float4(__expf(tv.x), __expf(tv.y),
                           __expf(tv.z), __expf(tv.w));
    }
  }

  const float* fb = feats + (size_t)b * TT * KK + lane;

  // ---- prefetch ring: slot (t-1)%7 holds u_t ----
  float upf[7];
  #pragma unroll
  for (int d = 0; d < 7; ++d) upf[d] = fb[(size_t)(1 + d) * KK];

  float beta  = (lane == START_TAG) ? 1.0f : 0.0f;
  int   esum  = 0;                      // sum of pow2 exponents (exact)
  float f_cur = __expf(upf[0]);         // exp(u_1)

  for (int g = 0; g < 73; ++g) {
    #pragma unroll
    for (int d = 0; d < 7; ++d) {
      const int t = 1 + g * 7 + d;

      // z_i = sum_j E[i][j] * beta[j]; beta[j] broadcast via readlane->SGPR.
      // 8 independent accumulator chains; readlanes are all independent.
      float4 a0 = {0.f, 0.f, 0.f, 0.f};
      float4 a1 = {0.f, 0.f, 0.f, 0.f};
      #pragma unroll
      for (int jc = 0; jc < 16; jc += 2) {
        a0.x = fmaf(e4[jc].x,     RLF(beta, 4*jc + 0), a0.x);
        a0.y = fmaf(e4[jc].y,     RLF(beta, 4*jc + 1), a0.y);
        a0.z = fmaf(e4[jc].z,     RLF(beta, 4*jc + 2), a0.z);
        a0.w = fmaf(e4[jc].w,     RLF(beta, 4*jc + 3), a0.w);
        a1.x = fmaf(e4[jc + 1].x, RLF(beta, 4*jc + 4), a1.x);
        a1.y = fmaf(e4[jc + 1].y, RLF(beta, 4*jc + 5), a1.y);
        a1.z = fmaf(e4[jc + 1].z, RLF(beta, 4*jc + 6), a1.z);
        a1.w = fmaf(e4[jc + 1].w, RLF(beta, 4*jc + 7), a1.w);
      }
      float z = ((a0.x + a1.x) + (a0.y + a1.y)) +
                ((a0.z + a1.z) + (a0.w + a1.w));

      // refill slot d with u_{t+7} (clamped; slot consumed at step t-1)
      int tn = t + 7; if (tn > TT - 1) tn = TT - 1;
      upf[d] = fb[(size_t)tn * KK];

      // ---- fresh pow2 normalization; exponent bookkeeping on SALU ----
      unsigned zb = (unsigned)__builtin_amdgcn_readlane((int)__float_as_uint(z), 0);
      float s = __uint_as_float(0x7F000000u - (zb & 0x7F800000u)); // 2^-(e-127)
      esum += (int)((zb >> 23) & 0xFFu) - 127;
      beta = (z * f_cur) * s;           // z*f issues while s resolves

      // next step's feat factor (off critical path; feats don't feed back)
      f_cur = __expf((d < 6) ? upf[d + 1] : upf[0]);
    }
  }

  // forward score = log(sum_j beta) + esum*ln2
  float bs = beta;
  #pragma unroll
  for (int off = 32; off; off >>= 1) bs += __shfl_xor(bs, off);
  float fwd = __logf(bs) + (float)esum * 0.6931471805599453f;

  // ---- gold path score ----
  const int* tg = tags + b * TT;
  float gs = 0.0f;
  for (int tt = 1 + lane; tt < TT; tt += 64) {
    int tc = tg[tt];
    int tp = tg[tt - 1];
    gs += trans[tc * KK + tp]
        + feats[(size_t)b * TT * KK + (size_t)tt * KK + tc];
  }
  #pragma unroll
  for (int off = 32; off; off >>= 1) gs += __shfl_xor(gs, off);

  if (lane == 0) diff[b] = fwd - gs;
}

__global__ __launch_bounds__(1024) void reduce_mean_kernel(
    const float* __restrict__ diff, float* __restrict__ out)
{
  __shared__ float part[16];
  const int tid = threadIdx.x;
  float v = diff[tid];
  #pragma unroll
  for (int off = 32; off; off >>= 1) v += __shfl_xor(v, off);
  if ((tid & 63) == 0) part[tid >> 6] = v;
  __syncthreads();
  if (tid < 16) {
    float s = part[tid];
    #pragma unroll
    for (int off = 8; off; off >>= 1) s += __shfl_xor(s, off);
    if (tid == 0) out[0] = s * (1.0f / 1024.0f);
  }
}

extern "C" void kernel_launch(void* const* d_in, const int* in_sizes, int n_in,
                              void* d_out, int out_size, void* d_ws, size_t ws_size,
                              hipStream_t stream) {
  const float* feats = (const float*)d_in[0];
  const int*   tags  = (const int*)d_in[1];
  const float* trans = (const float*)d_in[2];
  float* out  = (float*)d_out;
  float* diff = (float*)d_ws;   // 1024 floats of scratch

  crf_forward_kernel<<<dim3(BB), dim3(64), 0, stream>>>(feats, tags, trans, diff);
  reduce_mean_kernel<<<dim3(1), dim3(1024), 0, stream>>>(diff, out);
}